// Round 4
// baseline (492.592 us; speedup 1.0000x reference)
//
#include <hip/hip_runtime.h>
#include <hip/hip_bf16.h>
#include <stdint.h>

typedef __attribute__((ext_vector_type(4))) float  f32x4;
typedef __attribute__((ext_vector_type(8))) short  bf16x8;
typedef __attribute__((ext_vector_type(4))) float  float4v;
typedef __attribute__((ext_vector_type(4))) unsigned short u16x4;

typedef uint32_t u32_as1 __attribute__((address_space(1)));
typedef uint32_t u32_as3 __attribute__((address_space(3)));

__device__ __forceinline__ void gload_lds16(const void* g, void* l) {
  __builtin_amdgcn_global_load_lds((const u32_as1*)g, (u32_as3*)l, 16, 0, 0);
}

__device__ __forceinline__ unsigned short f2bf(float f) {
  union { float f; uint32_t u; } v; v.f = f;
  uint32_t r = v.u + 0x7fffu + ((v.u >> 16) & 1u);
  return (unsigned short)(r >> 16);
}
// round-to-nearest (ties away): 2 VALU ops, same max error as RNE
__device__ __forceinline__ unsigned short f2bf_fast(float f) {
  union { float f; uint32_t u; } v; v.f = f;
  return (unsigned short)((v.u + 0x8000u) >> 16);
}
__device__ __forceinline__ float bf2f(unsigned short u) {
  union { uint32_t u; float f; } v; v.u = ((uint32_t)u) << 16;
  return v.f;
}

// ---------------- elementwise f32 -> bf16 ----------------
__global__ __launch_bounds__(256) void cvt_f32_bf16(const float* __restrict__ in,
                                                    unsigned short* __restrict__ out,
                                                    int n4) {
  int i = blockIdx.x * 256 + threadIdx.x;
  if (i >= n4) return;
  float4v v = *(const float4v*)(in + (size_t)i * 4);
  u16x4 o;
  o.x = f2bf(v.x); o.y = f2bf(v.y); o.z = f2bf(v.z); o.w = f2bf(v.w);
  *(u16x4*)(out + (size_t)i * 4) = o;
}

// ---------------- weight transpose f32 -> bf16: WT[n][k] = W[k][n] ----------------
__global__ __launch_bounds__(256) void wtrans(const float* __restrict__ W,
                                              unsigned short* __restrict__ WT, int D) {
  __shared__ float tile[32][33];
  int r0 = blockIdx.x * 32;
  int c0 = blockIdx.y * 32;
  int tc = threadIdx.x & 31;
  int tr = (threadIdx.x >> 5) * 4;
#pragma unroll
  for (int i = 0; i < 4; i++)
    tile[tr + i][tc] = W[(size_t)(r0 + tr + i) * D + c0 + tc];
  __syncthreads();
#pragma unroll
  for (int i = 0; i < 4; i++)
    WT[(size_t)(c0 + tr + i) * D + r0 + tc] = f2bf(tile[tc][tr + i]);
}

// ---------------- bf16 transpose: Vt[c][r] = V[r][c] ----------------
__global__ __launch_bounds__(256) void btrans(const unsigned short* __restrict__ Vv,
                                              unsigned short* __restrict__ Vt,
                                              int R, int Cc) {
  __shared__ unsigned short tile[32][33];
  int r0 = blockIdx.x * 32;
  int c0 = blockIdx.y * 32;
  int tc = threadIdx.x & 31;
  int tr = (threadIdx.x >> 5) * 4;
#pragma unroll
  for (int i = 0; i < 4; i++)
    tile[tr + i][tc] = Vv[(size_t)(r0 + tr + i) * Cc + c0 + tc];
  __syncthreads();
#pragma unroll
  for (int i = 0; i < 4; i++)
    Vt[(size_t)(c0 + tr + i) * R + r0 + tc] = tile[tc][tr + i];
}

// ---------------- GEMM: C[M,N] = A[M,K] @ BT[N,K]^T + bias, optional relu+residual ----------------
__global__ __launch_bounds__(256) void gemm_bias(
    const unsigned short* __restrict__ A,    // [M,K] bf16
    const unsigned short* __restrict__ BT,   // [N,K] bf16
    const float* __restrict__ bias,          // [N]
    unsigned short* __restrict__ C,          // [M,N] bf16
    const unsigned short* __restrict__ RES,  // [M,N] bf16 (residual) or null
    int M, int N, int K, int relu_res) {
  __shared__ __align__(16) unsigned short Asm[128 * 32];
  __shared__ __align__(16) unsigned short Bsm[128 * 32];
  int tid = threadIdx.x;
  int lane = tid & 63;
  int w = tid >> 6;
  int wr = (w >> 1) * 64;
  int wc = (w & 1) * 64;
  int bm = blockIdx.x * 128;
  int bn = blockIdx.y * 128;
  int r = lane & 15;
  int q4 = lane >> 4;

  f32x4 acc[4][4] = {};

  for (int k0 = 0; k0 < K; k0 += 32) {
#pragma unroll
    for (int i = 0; i < 2; i++) {
      int idx = i * 256 + tid;        // 0..511
      int row = idx >> 2;             // 0..127
      int cb8 = (idx & 3) * 8;        // 0,8,16,24
      gload_lds16(A + (size_t)(bm + row) * K + k0 + cb8, &Asm[idx * 8]);
      gload_lds16(BT + (size_t)(bn + row) * K + k0 + cb8, &Bsm[idx * 8]);
    }
    __syncthreads();
    bf16x8 af[4], bfr[4];
#pragma unroll
    for (int mb = 0; mb < 4; mb++)
      af[mb] = *(const bf16x8*)&Asm[(wr + mb * 16 + r) * 32 + q4 * 8];
#pragma unroll
    for (int nb = 0; nb < 4; nb++)
      bfr[nb] = *(const bf16x8*)&Bsm[(wc + nb * 16 + r) * 32 + q4 * 8];
#pragma unroll
    for (int mb = 0; mb < 4; mb++)
#pragma unroll
      for (int nb = 0; nb < 4; nb++)
        acc[mb][nb] = __builtin_amdgcn_mfma_f32_16x16x32_bf16(af[mb], bfr[nb], acc[mb][nb], 0, 0, 0);
    __syncthreads();
  }

#pragma unroll
  for (int mb = 0; mb < 4; mb++) {
#pragma unroll
    for (int nb = 0; nb < 4; nb++) {
      int col = bn + wc + nb * 16 + r;
      float bv = bias[col];
#pragma unroll
      for (int rr = 0; rr < 4; rr++) {
        int row = bm + wr + mb * 16 + q4 * 4 + rr;
        float v = acc[mb][nb][rr] + bv;
        if (relu_res) {
          float res = bf2f(RES[(size_t)row * N + col]);
          v = res + (v > 0.f ? v : 0.f);
        }
        C[(size_t)row * N + col] = f2bf(v);
      }
    }
  }
}

// ---------------- flash attention, no-max softmax, Nk-split partials ----------------
// grid (Nq/128, H, 2), block 256 (4 waves). Wave w handles 32 q rows.
// Each z-split handles Nk/2 keys; writes unnormalized PV partial (bf16) + row-sum l (f32).
// launch_bounds min-waves=2: VGPR cap 128 -> NO spill (min=4 forced 64 VGPR and spilled
// ~900MB of scratch traffic to HBM in round 3).
__global__ __launch_bounds__(256, 2) void attn_kernel(
    const unsigned short* __restrict__ Q,    // [Nq,1024] bf16
    const unsigned short* __restrict__ Kp,   // [Nk,1024] bf16
    const unsigned short* __restrict__ Vt,   // [1024,Nk] bf16 (V transposed)
    unsigned short* __restrict__ Opart,      // [2][Nq,1024] bf16, unnormalized
    float* __restrict__ Lpart,               // [2][16][Nq] f32 row sums
    int Nq, int Nk) {
  __shared__ __align__(16) unsigned short P_lds[8][16][72];
  const int Dm = 1024;
  const float cexp = (1.0f / 32.0f) * 1.44269504088896f;  // scale * log2(e)
  int tid = threadIdx.x;
  int w = tid >> 6;
  int lane = tid & 63;
  int r = lane & 15;
  int q4 = lane >> 4;
  int h = blockIdx.y;
  int z = blockIdx.z;
  int qw = blockIdx.x * 128 + w * 32;
  int k_beg = z * (Nk >> 1);
  int k_end = k_beg + (Nk >> 1);

  const unsigned short* Kb = Kp + h * 64;
  const unsigned short* Vb = Vt + (size_t)h * 64 * Nk;

  bf16x8 qf[2][2];
#pragma unroll
  for (int mb = 0; mb < 2; mb++)
#pragma unroll
    for (int s = 0; s < 2; s++)
      qf[mb][s] = *(const bf16x8*)(Q + (size_t)(qw + mb * 16 + r) * Dm + h * 64 + s * 32 + q4 * 8);

  f32x4 acc[2][4] = {};
  float l_r[2][4] = {};

  // prefetch first K-tile into registers
  bf16x8 kf[8];
#pragma unroll
  for (int s = 0; s < 2; s++)
#pragma unroll
    for (int cb = 0; cb < 4; cb++)
      kf[s * 4 + cb] = *(const bf16x8*)(Kb + (size_t)(k_beg + cb * 16 + r) * Dm + s * 32 + q4 * 8);

  for (int key0 = k_beg; key0 < k_end; key0 += 64) {
    // QK^T
    f32x4 sacc[2][4] = {};
#pragma unroll
    for (int s = 0; s < 2; s++)
#pragma unroll
      for (int cb = 0; cb < 4; cb++)
#pragma unroll
        for (int mb = 0; mb < 2; mb++)
          sacc[mb][cb] = __builtin_amdgcn_mfma_f32_16x16x32_bf16(qf[mb][s], kf[s * 4 + cb], sacc[mb][cb], 0, 0, 0);

    // prefetch next K-tile (hides under exp + PV)
    int kn = key0 + 64;
    if (kn < k_end) {
#pragma unroll
      for (int s = 0; s < 2; s++)
#pragma unroll
        for (int cb = 0; cb < 4; cb++)
          kf[s * 4 + cb] = *(const bf16x8*)(Kb + (size_t)(kn + cb * 16 + r) * Dm + s * 32 + q4 * 8);
    }

    // exp (no max subtraction) + row-sum + P -> LDS (transposed layout)
#pragma unroll
    for (int mb = 0; mb < 2; mb++)
#pragma unroll
      for (int cb = 0; cb < 4; cb++)
#pragma unroll
        for (int rr = 0; rr < 4; rr++) {
          float p = __builtin_exp2f(sacc[mb][cb][rr] * cexp);
          l_r[mb][rr] += p;
          P_lds[w * 2 + mb][q4 * 4 + rr][r + cb * 16] = f2bf_fast(p);
        }

    // PV
#pragma unroll
    for (int s = 0; s < 2; s++) {
      bf16x8 pf0 = *(const bf16x8*)&P_lds[w * 2 + 0][r][s * 32 + q4 * 8];
      bf16x8 pf1 = *(const bf16x8*)&P_lds[w * 2 + 1][r][s * 32 + q4 * 8];
#pragma unroll
      for (int db = 0; db < 4; db++) {
        bf16x8 vf = *(const bf16x8*)(Vb + (size_t)(db * 16 + r) * Nk + key0 + s * 32 + q4 * 8);
        acc[0][db] = __builtin_amdgcn_mfma_f32_16x16x32_bf16(pf0, vf, acc[0][db], 0, 0, 0);
        acc[1][db] = __builtin_amdgcn_mfma_f32_16x16x32_bf16(pf1, vf, acc[1][db], 0, 0, 0);
      }
    }
  }

  // reduce l across the 16-lane group
#pragma unroll
  for (int mb = 0; mb < 2; mb++)
#pragma unroll
    for (int rr = 0; rr < 4; rr++) {
      float l = l_r[mb][rr];
#pragma unroll
      for (int m = 1; m < 16; m <<= 1) l += __shfl_xor(l, m);
      l_r[mb][rr] = l;
    }
  if (r == 0) {
#pragma unroll
    for (int mb = 0; mb < 2; mb++)
#pragma unroll
      for (int rr = 0; rr < 4; rr++)
        Lpart[(size_t)(z * 16 + h) * Nq + qw + mb * 16 + q4 * 4 + rr] = l_r[mb][rr];
  }

  unsigned short* Op = Opart + (size_t)z * Nq * Dm;
#pragma unroll
  for (int mb = 0; mb < 2; mb++)
#pragma unroll
    for (int db = 0; db < 4; db++)
#pragma unroll
      for (int rr = 0; rr < 4; rr++) {
        int qrow = qw + mb * 16 + q4 * 4 + rr;
        int col = h * 64 + db * 16 + r;
        Op[(size_t)qrow * Dm + col] = f2bf(acc[mb][db][rr]);
      }
}

// ---------------- combine splits + Q residual + LayerNorm1 (block per row) ----------------
__global__ __launch_bounds__(256) void combine_ln(
    const unsigned short* __restrict__ Q,    // [Nq,1024] bf16
    const unsigned short* __restrict__ Op,   // [2][Nq,1024] bf16
    const float* __restrict__ Lp,            // [2][16][Nq]
    const float* __restrict__ g, const float* __restrict__ b,
    unsigned short* __restrict__ out, int Nq) {
  int row = blockIdx.x;
  int tid = threadIdx.x;
  int h = tid >> 4;  // (tid*4)>>6
  size_t base = (size_t)row * 1024 + tid * 4;
  float linv = 1.0f / (Lp[(size_t)h * Nq + row] + Lp[(size_t)(16 + h) * Nq + row]);
  u16x4 qv = *(const u16x4*)(Q + base);
  u16x4 a0 = *(const u16x4*)(Op + base);
  u16x4 a1 = *(const u16x4*)(Op + (size_t)Nq * 1024 + base);
  float x0 = bf2f(qv.x) + (bf2f(a0.x) + bf2f(a1.x)) * linv;
  float x1 = bf2f(qv.y) + (bf2f(a0.y) + bf2f(a1.y)) * linv;
  float x2 = bf2f(qv.z) + (bf2f(a0.z) + bf2f(a1.z)) * linv;
  float x3 = bf2f(qv.w) + (bf2f(a0.w) + bf2f(a1.w)) * linv;
  float s = x0 + x1 + x2 + x3;
  float s2 = x0 * x0 + x1 * x1 + x2 * x2 + x3 * x3;
#pragma unroll
  for (int m = 1; m < 64; m <<= 1) { s += __shfl_xor(s, m); s2 += __shfl_xor(s2, m); }
  __shared__ float red[8];
  int w = tid >> 6, lane = tid & 63;
  if (lane == 0) { red[w] = s; red[4 + w] = s2; }
  __syncthreads();
  s = red[0] + red[1] + red[2] + red[3];
  s2 = red[4] + red[5] + red[6] + red[7];
  float mean = s * (1.0f / 1024.0f);
  float var = s2 * (1.0f / 1024.0f) - mean * mean;
  float inv = rsqrtf(var + 1e-5f);
  float y0 = (x0 - mean) * inv * g[tid * 4 + 0] + b[tid * 4 + 0];
  float y1 = (x1 - mean) * inv * g[tid * 4 + 1] + b[tid * 4 + 1];
  float y2 = (x2 - mean) * inv * g[tid * 4 + 2] + b[tid * 4 + 2];
  float y3 = (x3 - mean) * inv * g[tid * 4 + 3] + b[tid * 4 + 3];
  u16x4 o = {f2bf(y0), f2bf(y1), f2bf(y2), f2bf(y3)};
  *(u16x4*)(out + base) = o;
}

// ---------------- LayerNorm (block per row, D=1024) ----------------
template <int OUTF32>
__global__ __launch_bounds__(256) void ln_kernel(
    const unsigned short* __restrict__ X,  // bf16 [N,D]
    const float* __restrict__ g, const float* __restrict__ b,
    void* __restrict__ outp, int D) {
  int row = blockIdx.x;
  int tid = threadIdx.x;
  const unsigned short* xr = X + (size_t)row * D;
  u16x4 xv = *(const u16x4*)(xr + tid * 4);
  float x0 = bf2f(xv.x), x1 = bf2f(xv.y), x2 = bf2f(xv.z), x3 = bf2f(xv.w);
  float s = x0 + x1 + x2 + x3;
  float s2 = x0 * x0 + x1 * x1 + x2 * x2 + x3 * x3;
#pragma unroll
  for (int m = 1; m < 64; m <<= 1) { s += __shfl_xor(s, m); s2 += __shfl_xor(s2, m); }
  __shared__ float red[8];
  int w = tid >> 6, lane = tid & 63;
  if (lane == 0) { red[w] = s; red[4 + w] = s2; }
  __syncthreads();
  s = red[0] + red[1] + red[2] + red[3];
  s2 = red[4] + red[5] + red[6] + red[7];
  float mean = s * (1.0f / 1024.0f);
  float var = s2 * (1.0f / 1024.0f) - mean * mean;
  float inv = rsqrtf(var + 1e-5f);
  float y0 = (x0 - mean) * inv * g[tid * 4 + 0] + b[tid * 4 + 0];
  float y1 = (x1 - mean) * inv * g[tid * 4 + 1] + b[tid * 4 + 1];
  float y2 = (x2 - mean) * inv * g[tid * 4 + 2] + b[tid * 4 + 2];
  float y3 = (x3 - mean) * inv * g[tid * 4 + 3] + b[tid * 4 + 3];
  if (OUTF32) {
    float4v o = {y0, y1, y2, y3};
    *(float4v*)((float*)outp + (size_t)row * D + tid * 4) = o;
  } else {
    u16x4 o = {f2bf(y0), f2bf(y1), f2bf(y2), f2bf(y3)};
    *(u16x4*)((unsigned short*)outp + (size_t)row * D + tid * 4) = o;
  }
}

extern "C" void kernel_launch(void* const* d_in, const int* in_sizes, int n_in,
                              void* d_out, int out_size, void* d_ws, size_t ws_size,
                              hipStream_t stream) {
  (void)in_sizes; (void)n_in; (void)out_size; (void)ws_size;
  const float* query = (const float*)d_in[0];
  const float* key_  = (const float*)d_in[1];
  const float* Wq = (const float*)d_in[2];
  const float* bq = (const float*)d_in[3];
  const float* Wk = (const float*)d_in[4];
  const float* bk = (const float*)d_in[5];
  const float* Wv = (const float*)d_in[6];
  const float* bv = (const float*)d_in[7];
  const float* g1 = (const float*)d_in[8];
  const float* b1 = (const float*)d_in[9];
  const float* Wl = (const float*)d_in[10];
  const float* bl = (const float*)d_in[11];
  const float* g2 = (const float*)d_in[12];
  const float* b2 = (const float*)d_in[13];
  float* out = (float*)d_out;

  const int Nq = 4096, Nk = 4096, D = 1024;
  const size_t MEl = (size_t)4096 * 1024;  // 4M elements

  unsigned short* w16 = (unsigned short*)d_ws;
  unsigned short* qb  = w16;                 // 4M el
  unsigned short* kb  = w16 + MEl;           // 4M el
  unsigned short* WqT = w16 + 2 * MEl;       // 1M el
  unsigned short* WkT = WqT + (size_t)D * D;
  unsigned short* WvT = WkT + (size_t)D * D;
  unsigned short* WlT = WvT + (size_t)D * D;
  unsigned short* Qp  = WlT + (size_t)D * D; // 4M el
  unsigned short* Kp  = Qp + MEl;
  unsigned short* Vp  = Kp + MEl;
  unsigned short* Vt  = Vp + MEl;
  float* Lpart = (float*)(Vt + MEl);         // 2*16*4096 f32 = 512 KB
  // reuse dead regions:
  unsigned short* Opart = qb;   // [2][Nq,1024] = qb(4M)+kb(4M), both dead after GEMMs
  unsigned short* out1  = Vp;   // V dead after transpose
  unsigned short* out2  = qb;   // Opart dead after combine_ln

  cvt_f32_bf16<<<4096, 256, 0, stream>>>(query, qb, (int)(MEl / 4));
  cvt_f32_bf16<<<4096, 256, 0, stream>>>(key_, kb, (int)(MEl / 4));
  dim3 gw(32, 32);
  wtrans<<<gw, 256, 0, stream>>>(Wq, WqT, D);
  wtrans<<<gw, 256, 0, stream>>>(Wk, WkT, D);
  wtrans<<<gw, 256, 0, stream>>>(Wv, WvT, D);
  wtrans<<<gw, 256, 0, stream>>>(Wl, WlT, D);

  dim3 gg(32, 8);  // (M/128, N/128)
  gemm_bias<<<gg, 256, 0, stream>>>(qb, WqT, bq, Qp, nullptr, Nq, D, D, 0);
  gemm_bias<<<gg, 256, 0, stream>>>(kb, WkT, bk, Kp, nullptr, Nk, D, D, 0);
  gemm_bias<<<gg, 256, 0, stream>>>(kb, WvT, bv, Vp, nullptr, Nk, D, D, 0);

  btrans<<<dim3(128, 32), 256, 0, stream>>>(Vp, Vt, Nk, D);

  attn_kernel<<<dim3(Nq / 128, 16, 2), 256, 0, stream>>>(Qp, Kp, Vt, Opart, Lpart, Nq, Nk);

  combine_ln<<<4096, 256, 0, stream>>>(Qp, Opart, Lpart, g1, b1, out1, Nq);
  gemm_bias<<<gg, 256, 0, stream>>>(out1, WlT, bl, out2, out1, Nq, D, D, 1);
  ln_kernel<1><<<4096, 256, 0, stream>>>(out2, g2, b2, (void*)out, D);
}

// Round 5
// 381.976 us; speedup vs baseline: 1.2896x; 1.2896x over previous
//
#include <hip/hip_runtime.h>
#include <hip/hip_bf16.h>
#include <stdint.h>

typedef __attribute__((ext_vector_type(4))) float  f32x4;
typedef __attribute__((ext_vector_type(8))) short  bf16x8;
typedef __attribute__((ext_vector_type(4))) float  float4v;
typedef __attribute__((ext_vector_type(4))) unsigned short u16x4;

typedef uint32_t u32_as1 __attribute__((address_space(1)));
typedef uint32_t u32_as3 __attribute__((address_space(3)));

#define CEXP_SCALE 0.045084221f   /* (1/32) * log2(e) */
#define INV_CEXP   22.180710f     /* 32 * ln(2) */

__device__ __forceinline__ void gload_lds16(const void* g, void* l) {
  __builtin_amdgcn_global_load_lds((const u32_as1*)g, (u32_as3*)l, 16, 0, 0);
}

__device__ __forceinline__ unsigned short f2bf(float f) {
  union { float f; uint32_t u; } v; v.f = f;
  uint32_t r = v.u + 0x7fffu + ((v.u >> 16) & 1u);
  return (unsigned short)(r >> 16);
}
// round-to-nearest (ties away): 2 VALU ops
__device__ __forceinline__ unsigned short f2bf_fast(float f) {
  union { float f; uint32_t u; } v; v.f = f;
  return (unsigned short)((v.u + 0x8000u) >> 16);
}
__device__ __forceinline__ float bf2f(unsigned short u) {
  union { uint32_t u; float f; } v; v.u = ((uint32_t)u) << 16;
  return v.f;
}

// ---------------- elementwise f32 -> bf16 ----------------
__global__ __launch_bounds__(256) void cvt_f32_bf16(const float* __restrict__ in,
                                                    unsigned short* __restrict__ out,
                                                    int n4) {
  int i = blockIdx.x * 256 + threadIdx.x;
  if (i >= n4) return;
  float4v v = *(const float4v*)(in + (size_t)i * 4);
  u16x4 o;
  o.x = f2bf(v.x); o.y = f2bf(v.y); o.z = f2bf(v.z); o.w = f2bf(v.w);
  *(u16x4*)(out + (size_t)i * 4) = o;
}

// ---------------- weight transpose f32 -> bf16: WT[n][k] = W[k][n] ----------------
__global__ __launch_bounds__(256) void wtrans(const float* __restrict__ W,
                                              unsigned short* __restrict__ WT, int D) {
  __shared__ float tile[32][33];
  int r0 = blockIdx.x * 32;
  int c0 = blockIdx.y * 32;
  int tc = threadIdx.x & 31;
  int tr = (threadIdx.x >> 5) * 4;
#pragma unroll
  for (int i = 0; i < 4; i++)
    tile[tr + i][tc] = W[(size_t)(r0 + tr + i) * D + c0 + tc];
  __syncthreads();
#pragma unroll
  for (int i = 0; i < 4; i++)
    WT[(size_t)(c0 + tr + i) * D + r0 + tc] = f2bf(tile[tc][tr + i]);
}

// ---------------- bf16 transpose: Vt[c][r] = V[r][c] ----------------
__global__ __launch_bounds__(256) void btrans(const unsigned short* __restrict__ Vv,
                                              unsigned short* __restrict__ Vt,
                                              int R, int Cc) {
  __shared__ unsigned short tile[32][33];
  int r0 = blockIdx.x * 32;
  int c0 = blockIdx.y * 32;
  int tc = threadIdx.x & 31;
  int tr = (threadIdx.x >> 5) * 4;
#pragma unroll
  for (int i = 0; i < 4; i++)
    tile[tr + i][tc] = Vv[(size_t)(r0 + tr + i) * Cc + c0 + tc];
  __syncthreads();
#pragma unroll
  for (int i = 0; i < 4; i++)
    Vt[(size_t)(c0 + tr + i) * R + r0 + tc] = tile[tc][tr + i];
}

// ---------------- GEMM: C = A @ BT^T + bias, optional relu+residual, scaled store ----------------
__global__ __launch_bounds__(256) void gemm_bias(
    const unsigned short* __restrict__ A,    // [M,K] bf16
    const unsigned short* __restrict__ BT,   // [N,K] bf16
    const float* __restrict__ bias,          // [N]
    unsigned short* __restrict__ C,          // [M,N] bf16
    const unsigned short* __restrict__ RES,  // [M,N] bf16 (residual) or null
    int M, int N, int K, int relu_res, float cscale) {
  __shared__ __align__(16) unsigned short Asm[128 * 32];
  __shared__ __align__(16) unsigned short Bsm[128 * 32];
  int tid = threadIdx.x;
  int lane = tid & 63;
  int w = tid >> 6;
  int wr = (w >> 1) * 64;
  int wc = (w & 1) * 64;
  int bm = blockIdx.x * 128;
  int bn = blockIdx.y * 128;
  int r = lane & 15;
  int q4 = lane >> 4;

  f32x4 acc[4][4] = {};

  for (int k0 = 0; k0 < K; k0 += 32) {
#pragma unroll
    for (int i = 0; i < 2; i++) {
      int idx = i * 256 + tid;        // 0..511
      int row = idx >> 2;             // 0..127
      int cb8 = (idx & 3) * 8;        // 0,8,16,24
      gload_lds16(A + (size_t)(bm + row) * K + k0 + cb8, &Asm[idx * 8]);
      gload_lds16(BT + (size_t)(bn + row) * K + k0 + cb8, &Bsm[idx * 8]);
    }
    __syncthreads();
    bf16x8 af[4], bfr[4];
#pragma unroll
    for (int mb = 0; mb < 4; mb++)
      af[mb] = *(const bf16x8*)&Asm[(wr + mb * 16 + r) * 32 + q4 * 8];
#pragma unroll
    for (int nb = 0; nb < 4; nb++)
      bfr[nb] = *(const bf16x8*)&Bsm[(wc + nb * 16 + r) * 32 + q4 * 8];
#pragma unroll
    for (int mb = 0; mb < 4; mb++)
#pragma unroll
      for (int nb = 0; nb < 4; nb++)
        acc[mb][nb] = __builtin_amdgcn_mfma_f32_16x16x32_bf16(af[mb], bfr[nb], acc[mb][nb], 0, 0, 0);
    __syncthreads();
  }

#pragma unroll
  for (int mb = 0; mb < 4; mb++) {
#pragma unroll
    for (int nb = 0; nb < 4; nb++) {
      int col = bn + wc + nb * 16 + r;
      float bv = bias[col];
#pragma unroll
      for (int rr = 0; rr < 4; rr++) {
        int row = bm + wr + mb * 16 + q4 * 4 + rr;
        float v = acc[mb][nb][rr] + bv;
        if (relu_res) {
          float res = bf2f(RES[(size_t)row * N + col]);
          v = res + (v > 0.f ? v : 0.f);
        }
        C[(size_t)row * N + col] = f2bf(v * cscale);
      }
    }
  }
}

// ---------------- flash attention, no-max softmax, PV-shifted pipeline ----------------
// grid (Nq/128, H), block 256 (4 waves). Wave w handles 32 q rows (2 row-blocks).
// Qs is pre-scaled by scale*log2(e); residual recovered via INV_CEXP.
// Per iter: QK(t) -> loadK(t+1) -> PV(t-1) -> loadV(t) -> exp/write P(t).
// Row-sums accumulated by MFMA against a constant ones B-frag.
__global__ __launch_bounds__(256) void attn_kernel(
    const unsigned short* __restrict__ Qs,   // [Nq,1024] bf16, pre-scaled
    const unsigned short* __restrict__ Kp,   // [Nk,1024] bf16
    const unsigned short* __restrict__ Vt,   // [1024,Nk] bf16 (V transposed)
    unsigned short* __restrict__ O,          // [Nq,1024] bf16
    int Nq, int Nk) {
  __shared__ __align__(16) unsigned short P_lds[2][8][16][72];
  const int Dm = 1024;
  int tid = threadIdx.x;
  int w = tid >> 6;
  int lane = tid & 63;
  int r = lane & 15;
  int q4 = lane >> 4;
  int h = blockIdx.y;
  int qw = blockIdx.x * 128 + w * 32;
  const int NT = Nk >> 6;  // 64-key tiles

  const unsigned short* Kb = Kp + h * 64;
  const unsigned short* Vb = Vt + (size_t)h * 64 * Nk;

  bf16x8 qf[2][2];
#pragma unroll
  for (int mb = 0; mb < 2; mb++)
#pragma unroll
    for (int s = 0; s < 2; s++)
      qf[mb][s] = *(const bf16x8*)(Qs + (size_t)(qw + mb * 16 + r) * Dm + h * 64 + s * 32 + q4 * 8);

  // constant ones B-frag: row 0 of virtual block = 1.0, rest 0 -> col 0 = row-sum
  short ob = (r == 0) ? (short)0x3F80 : (short)0;
  bf16x8 ones = {ob, ob, ob, ob, ob, ob, ob, ob};

  f32x4 acc[2][4] = {};
  f32x4 acc_s[2] = {};
  f32x4 sacc[2][4];
  bf16x8 kf[8], vf[8];

  auto loadK = [&](int key0) {
#pragma unroll
    for (int s = 0; s < 2; s++)
#pragma unroll
      for (int cb = 0; cb < 4; cb++)
        kf[s * 4 + cb] = *(const bf16x8*)(Kb + (size_t)(key0 + cb * 16 + r) * Dm + s * 32 + q4 * 8);
  };
  auto loadV = [&](int key0) {
#pragma unroll
    for (int s = 0; s < 2; s++)
#pragma unroll
      for (int db = 0; db < 4; db++)
        vf[s * 4 + db] = *(const bf16x8*)(Vb + (size_t)(db * 16 + r) * Nk + key0 + s * 32 + q4 * 8);
  };
  auto doQK = [&]() {
#pragma unroll
    for (int mb = 0; mb < 2; mb++)
#pragma unroll
      for (int cb = 0; cb < 4; cb++)
        sacc[mb][cb] = f32x4{0.f, 0.f, 0.f, 0.f};
#pragma unroll
    for (int s = 0; s < 2; s++)
#pragma unroll
      for (int cb = 0; cb < 4; cb++)
#pragma unroll
        for (int mb = 0; mb < 2; mb++)
          sacc[mb][cb] = __builtin_amdgcn_mfma_f32_16x16x32_bf16(qf[mb][s], kf[s * 4 + cb], sacc[mb][cb], 0, 0, 0);
  };
  auto doEXP = [&](int buf) {
#pragma unroll
    for (int mb = 0; mb < 2; mb++)
#pragma unroll
      for (int cb = 0; cb < 4; cb++)
#pragma unroll
        for (int rr = 0; rr < 4; rr++) {
          float p = __builtin_exp2f(sacc[mb][cb][rr]);
          P_lds[buf][w * 2 + mb][q4 * 4 + rr][r + cb * 16] = f2bf_fast(p);
        }
  };
  auto doPV = [&](int buf) {
#pragma unroll
    for (int s = 0; s < 2; s++) {
      bf16x8 pf0 = *(const bf16x8*)&P_lds[buf][w * 2 + 0][r][s * 32 + q4 * 8];
      bf16x8 pf1 = *(const bf16x8*)&P_lds[buf][w * 2 + 1][r][s * 32 + q4 * 8];
      acc_s[0] = __builtin_amdgcn_mfma_f32_16x16x32_bf16(pf0, ones, acc_s[0], 0, 0, 0);
      acc_s[1] = __builtin_amdgcn_mfma_f32_16x16x32_bf16(pf1, ones, acc_s[1], 0, 0, 0);
#pragma unroll
      for (int db = 0; db < 4; db++) {
        bf16x8 vfx = vf[s * 4 + db];
        acc[0][db] = __builtin_amdgcn_mfma_f32_16x16x32_bf16(pf0, vfx, acc[0][db], 0, 0, 0);
        acc[1][db] = __builtin_amdgcn_mfma_f32_16x16x32_bf16(pf1, vfx, acc[1][db], 0, 0, 0);
      }
    }
  };

  // prologue: tile 0
  loadK(0);
  loadV(0);
  doQK();
  loadK(64);
  doEXP(0);

  for (int t = 1; t < NT; ++t) {
    int key0 = t * 64;
    doQK();                        // uses kf(t)
    if (t < NT - 1) loadK(key0 + 64);
    doPV((t - 1) & 1);             // uses vf(t-1), P(t-1)
    loadV(key0);                   // vf(t) for next iter's PV
    doEXP(t & 1);                  // write P(t)
  }
  doPV((NT - 1) & 1);

  // broadcast row-sums from r==0 lanes of each q4 group
#pragma unroll
  for (int mb = 0; mb < 2; mb++)
#pragma unroll
    for (int db = 0; db < 4; db++)
#pragma unroll
      for (int rr = 0; rr < 4; rr++) {
        float l = __shfl(acc_s[mb][rr], lane & 48);
        float linv = 1.0f / l;
        int qrow = qw + mb * 16 + q4 * 4 + rr;
        int col = h * 64 + db * 16 + r;
        float qv = bf2f(Qs[(size_t)qrow * Dm + col]) * INV_CEXP;
        O[(size_t)qrow * Dm + col] = f2bf(qv + acc[mb][db][rr] * linv);
      }
}

// ---------------- LayerNorm (block per row, D=1024) ----------------
template <int OUTF32>
__global__ __launch_bounds__(256) void ln_kernel(
    const unsigned short* __restrict__ X,  // bf16 [N,D]
    const float* __restrict__ g, const float* __restrict__ b,
    void* __restrict__ outp, int D) {
  int row = blockIdx.x;
  int tid = threadIdx.x;
  const unsigned short* xr = X + (size_t)row * D;
  u16x4 xv = *(const u16x4*)(xr + tid * 4);
  float x0 = bf2f(xv.x), x1 = bf2f(xv.y), x2 = bf2f(xv.z), x3 = bf2f(xv.w);
  float s = x0 + x1 + x2 + x3;
  float s2 = x0 * x0 + x1 * x1 + x2 * x2 + x3 * x3;
#pragma unroll
  for (int m = 1; m < 64; m <<= 1) { s += __shfl_xor(s, m); s2 += __shfl_xor(s2, m); }
  __shared__ float red[8];
  int w = tid >> 6, lane = tid & 63;
  if (lane == 0) { red[w] = s; red[4 + w] = s2; }
  __syncthreads();
  s = red[0] + red[1] + red[2] + red[3];
  s2 = red[4] + red[5] + red[6] + red[7];
  float mean = s * (1.0f / 1024.0f);
  float var = s2 * (1.0f / 1024.0f) - mean * mean;
  float inv = rsqrtf(var + 1e-5f);
  float y0 = (x0 - mean) * inv * g[tid * 4 + 0] + b[tid * 4 + 0];
  float y1 = (x1 - mean) * inv * g[tid * 4 + 1] + b[tid * 4 + 1];
  float y2 = (x2 - mean) * inv * g[tid * 4 + 2] + b[tid * 4 + 2];
  float y3 = (x3 - mean) * inv * g[tid * 4 + 3] + b[tid * 4 + 3];
  if (OUTF32) {
    float4v o = {y0, y1, y2, y3};
    *(float4v*)((float*)outp + (size_t)row * D + tid * 4) = o;
  } else {
    u16x4 o = {f2bf(y0), f2bf(y1), f2bf(y2), f2bf(y3)};
    *(u16x4*)((unsigned short*)outp + (size_t)row * D + tid * 4) = o;
  }
}

extern "C" void kernel_launch(void* const* d_in, const int* in_sizes, int n_in,
                              void* d_out, int out_size, void* d_ws, size_t ws_size,
                              hipStream_t stream) {
  (void)in_sizes; (void)n_in; (void)out_size; (void)ws_size;
  const float* query = (const float*)d_in[0];
  const float* key_  = (const float*)d_in[1];
  const float* Wq = (const float*)d_in[2];
  const float* bq = (const float*)d_in[3];
  const float* Wk = (const float*)d_in[4];
  const float* bk = (const float*)d_in[5];
  const float* Wv = (const float*)d_in[6];
  const float* bv = (const float*)d_in[7];
  const float* g1 = (const float*)d_in[8];
  const float* b1 = (const float*)d_in[9];
  const float* Wl = (const float*)d_in[10];
  const float* bl = (const float*)d_in[11];
  const float* g2 = (const float*)d_in[12];
  const float* b2 = (const float*)d_in[13];
  float* out = (float*)d_out;

  const int Nq = 4096, Nk = 4096, D = 1024;
  const size_t MEl = (size_t)4096 * 1024;  // 4M elements

  unsigned short* w16 = (unsigned short*)d_ws;
  unsigned short* qb  = w16;                 // 4M el
  unsigned short* kb  = w16 + MEl;           // 4M el
  unsigned short* WqT = w16 + 2 * MEl;       // 1M el
  unsigned short* WkT = WqT + (size_t)D * D;
  unsigned short* WvT = WkT + (size_t)D * D;
  unsigned short* WlT = WvT + (size_t)D * D;
  unsigned short* Qs  = WlT + (size_t)D * D; // 4M el (pre-scaled Q projection)
  unsigned short* Kp  = Qs + MEl;
  unsigned short* Vp  = Kp + MEl;
  unsigned short* Vt  = Vp + MEl;
  // reuse dead regions:
  unsigned short* Ob   = kb;   // key bf16 dead after K/V GEMMs
  unsigned short* out1 = Vp;   // V dead after transpose
  unsigned short* out2 = qb;   // query bf16 dead after Q GEMM

  cvt_f32_bf16<<<4096, 256, 0, stream>>>(query, qb, (int)(MEl / 4));
  cvt_f32_bf16<<<4096, 256, 0, stream>>>(key_, kb, (int)(MEl / 4));
  dim3 gw(32, 32);
  wtrans<<<gw, 256, 0, stream>>>(Wq, WqT, D);
  wtrans<<<gw, 256, 0, stream>>>(Wk, WkT, D);
  wtrans<<<gw, 256, 0, stream>>>(Wv, WvT, D);
  wtrans<<<gw, 256, 0, stream>>>(Wl, WlT, D);

  dim3 gg(32, 8);  // (M/128, N/128)
  gemm_bias<<<gg, 256, 0, stream>>>(qb, WqT, bq, Qs, nullptr, Nq, D, D, 0, CEXP_SCALE);
  gemm_bias<<<gg, 256, 0, stream>>>(kb, WkT, bk, Kp, nullptr, Nk, D, D, 0, 1.0f);
  gemm_bias<<<gg, 256, 0, stream>>>(kb, WvT, bv, Vp, nullptr, Nk, D, D, 0, 1.0f);

  btrans<<<dim3(128, 32), 256, 0, stream>>>(Vp, Vt, Nk, D);

  attn_kernel<<<dim3(Nq / 128, 16), 256, 0, stream>>>(Qs, Kp, Vt, Ob, Nq, Nk);

  ln_kernel<0><<<4096, 256, 0, stream>>>(Ob, g1, b1, (void*)out1, D);
  gemm_bias<<<gg, 256, 0, stream>>>(out1, WlT, bl, out2, out1, Nq, D, D, 1, 1.0f);
  ln_kernel<1><<<4096, 256, 0, stream>>>(out2, g2, b2, (void*)out, D);
}